// Round 5
// baseline (493.744 us; speedup 1.0000x reference)
//
#include <hip/hip_runtime.h>

typedef unsigned short u16;
typedef unsigned int u32;
typedef __bf16 bf16x8 __attribute__((ext_vector_type(8)));
typedef float f32x4 __attribute__((ext_vector_type(4)));

#define BATCH 4
#define SLEN 2048
#define DMODEL 1024
#define NHEAD 16
#define DHEAD 64
#define MROWS (BATCH * SLEN) /* 8192 */

__device__ __forceinline__ u16 f32_to_bf16(float f) {
  u32 u = __float_as_uint(f);
  u32 r = (u + 0x7FFFu + ((u >> 16) & 1u)) >> 16;
  return (u16)r;
}
__device__ __forceinline__ u32 pack_bf16x2(float a, float b) {
  return (u32)f32_to_bf16(a) | ((u32)f32_to_bf16(b) << 16);
}

// pack two f32 -> two bf16 (truncate), 1 v_perm_b32
__device__ __forceinline__ u32 pack_trunc(float lo, float hi) {
#if __has_builtin(__builtin_amdgcn_perm)
  return __builtin_amdgcn_perm(__float_as_uint(hi), __float_as_uint(lo), 0x07060302u);
#else
  return (__float_as_uint(hi) & 0xFFFF0000u) | (__float_as_uint(lo) >> 16);
#endif
}
// pack with round-half-up (epilogue)
__device__ __forceinline__ u32 pack_round(float lo, float hi) {
  u32 ul = __float_as_uint(lo) + 0x8000u;
  u32 uh = __float_as_uint(hi) + 0x8000u;
#if __has_builtin(__builtin_amdgcn_perm)
  return __builtin_amdgcn_perm(uh, ul, 0x07060302u);
#else
  return (uh & 0xFFFF0000u) | (ul >> 16);
#endif
}

#if __has_builtin(__builtin_amdgcn_exp2f)
#define EXP2(x) __builtin_amdgcn_exp2f(x)
#else
#define EXP2(x) exp2f(x)
#endif

// async global->LDS, 16 B per lane; lds dest = wave-uniform base + lane*16
typedef const __attribute__((address_space(1))) void* gas_cv;
typedef __attribute__((address_space(3))) void* las_v;
__device__ __forceinline__ void async16(const u16* g, u16* l) {
  __builtin_amdgcn_global_load_lds((gas_cv)g, (las_v)l, 16, 0, 0);
}

// ---------------- prep kernels ----------------

__global__ void convert_x_kernel(const float* __restrict__ x, u16* __restrict__ xb) {
  size_t i = ((size_t)blockIdx.x * 256 + threadIdx.x) * 8;
  float4 v0 = *(const float4*)(x + i);
  float4 v1 = *(const float4*)(x + i + 4);
  uint4 o;
  o.x = pack_bf16x2(v0.x, v0.y);
  o.y = pack_bf16x2(v0.z, v0.w);
  o.z = pack_bf16x2(v1.x, v1.y);
  o.w = pack_bf16x2(v1.z, v1.w);
  *(uint4*)(xb + i) = o;
}

__global__ void transpose_w_kernel(const float* __restrict__ Wq, const float* __restrict__ Wk,
                                   const float* __restrict__ Wv, const float* __restrict__ Wo,
                                   u16* __restrict__ wqkvt, u16* __restrict__ wot) {
  __shared__ float tile[32][33];
  int z = blockIdx.z;
  const float* src = (z == 0) ? Wq : (z == 1) ? Wk : (z == 2) ? Wv : Wo;
  u16* dst = (z < 3) ? (wqkvt + (size_t)z * DMODEL * DMODEL) : wot;
  int c0 = blockIdx.x * 32, r0 = blockIdx.y * 32;
  int tx = threadIdx.x & 31, ty = threadIdx.x >> 5;
#pragma unroll
  for (int i = 0; i < 4; ++i)
    tile[ty + 8 * i][tx] = src[(size_t)(r0 + ty + 8 * i) * DMODEL + c0 + tx];
  __syncthreads();
#pragma unroll
  for (int i = 0; i < 4; ++i)
    dst[(size_t)(c0 + ty + 8 * i) * DMODEL + r0 + tx] = f32_to_bf16(tile[tx][ty + 8 * i]);
}

__global__ void concat_bias_kernel(const float* __restrict__ bq, const float* __restrict__ bk,
                                   const float* __restrict__ bv, float* __restrict__ bqkv) {
  int i = blockIdx.x * 256 + threadIdx.x;
  float v = (i < 1024) ? bq[i] : (i < 2048) ? bk[i - 1024] : bv[i - 2048];
  bqkv[i] = v;
}

// V slice of qkv [b][s][h*64+dh] -> vt [b][h][dh][s]
__global__ void transpose_v_kernel(const u16* __restrict__ qkv, u16* __restrict__ vt) {
  __shared__ u16 tile[32][33];
  const int bh = blockIdx.z;
  const int b = bh >> 4, h = bh & 15;
  const int s0 = blockIdx.x * 32, d0 = blockIdx.y * 32;
  const int tx = threadIdx.x & 31, ty = threadIdx.x >> 5;
#pragma unroll
  for (int i = 0; i < 4; ++i)
    tile[ty + 8 * i][tx] =
        qkv[(size_t)(b * SLEN + s0 + ty + 8 * i) * (3 * DMODEL) + 2 * DMODEL + h * DHEAD + d0 + tx];
  __syncthreads();
#pragma unroll
  for (int i = 0; i < 4; ++i)
    vt[(size_t)(bh * DHEAD + d0 + ty + 8 * i) * SLEN + s0 + tx] = tile[tx][ty + 8 * i];
}

// ---------------- GEMM with global_load_lds (m97 pattern, unchanged from R4) ----------------
template <int OUT_BF16>
__global__ __launch_bounds__(256) void gemm_bt_kernel(const u16* __restrict__ A,
                                                      const u16* __restrict__ Bt,
                                                      const float* __restrict__ bias,
                                                      void* __restrict__ Cout,
                                                      int M, int N, int K) {
  __shared__ u16 sA[128 * 32];
  __shared__ u16 sB[128 * 32];
  const int tid = threadIdx.x;
  const int wv = tid >> 6, lane = tid & 63;
  const int wr = wv >> 1, wc = wv & 1;
  const int col = lane & 15, quad = lane >> 4;
  const int m0 = blockIdx.x * 128;
  const int n0 = blockIdx.y * 128;

  f32x4 acc[4][4] = {};

  const int lr = tid >> 2;
  const int ls = tid & 3;
  const size_t a_base = (size_t)(m0 + lr) * K + ls * 8;
  const size_t b_base = (size_t)(n0 + lr) * K + ls * 8;
  u16* ldsA0 = sA + ((tid >> 6) << 9);
  u16* ldsA1 = ldsA0 + 2048;
  u16* ldsB0 = sB + ((tid >> 6) << 9);
  u16* ldsB1 = ldsB0 + 2048;

  for (int k0 = 0; k0 < K; k0 += 32) {
    async16(A + a_base + k0, ldsA0);
    async16(A + a_base + (size_t)64 * K + k0, ldsA1);
    async16(Bt + b_base + k0, ldsB0);
    async16(Bt + b_base + (size_t)64 * K + k0, ldsB1);
    __syncthreads();
    bf16x8 af[4], bfr[4];
#pragma unroll
    for (int i = 0; i < 4; ++i)
      af[i] = *(const bf16x8*)(sA + (wr * 64 + i * 16 + col) * 32 + quad * 8);
#pragma unroll
    for (int j = 0; j < 4; ++j)
      bfr[j] = *(const bf16x8*)(sB + (wc * 64 + j * 16 + col) * 32 + quad * 8);
#pragma unroll
    for (int i = 0; i < 4; ++i)
#pragma unroll
      for (int j = 0; j < 4; ++j)
        acc[i][j] = __builtin_amdgcn_mfma_f32_16x16x32_bf16(af[i], bfr[j], acc[i][j], 0, 0, 0);
    __syncthreads();
  }

#pragma unroll
  for (int i = 0; i < 4; ++i) {
#pragma unroll
    for (int j = 0; j < 4; ++j) {
      int n = n0 + wc * 64 + j * 16 + col;
      float bia = bias[n];
#pragma unroll
      for (int r = 0; r < 4; ++r) {
        int m = m0 + wr * 64 + i * 16 + quad * 4 + r;
        float v = acc[i][j][r] + bia;
        if (OUT_BF16)
          ((u16*)Cout)[(size_t)m * N + n] = f32_to_bf16(v);
        else
          ((float*)Cout)[(size_t)m * N + n] = v;
      }
    }
  }
}

// ---------------- flash attention v3: S^T formulation, wave-autonomous ----------------
// grid (16, BATCH*NHEAD), 256 thr = 4 waves, launch_bounds(256,3) -> 12 waves/CU.
// Wave owns one 32-q-row strip (longest strips dispatched first for backfill).
// S^T = mfma(K, Q): kv on C-row axis -> softmax reduce = 15 in-reg fmax + 2 shfl.
// O^T = mfma(V^T, P^T): P^T packed to LDS via v_perm (b64 writes), read as B-frags.
__global__ __launch_bounds__(256, 3) void attn_kernel(const u16* __restrict__ qkv,
                                                      const u16* __restrict__ vt,
                                                      u16* __restrict__ out) {
  const int bh = blockIdx.y;
  const int b = bh >> 4, h = bh & 15;
  const int tid = threadIdx.x;
  const int wv = tid >> 6, lane = tid & 63;
  const int col = lane & 15, quad = lane >> 4;
  const int s = 63 - ((int)blockIdx.x * 4 + wv); // strip 0..63, longest first
  const int qbase = s * 32;
  const int ntiles = s / 2 + 1;

  __shared__ u16 sP[4][32 * 72]; // per-wave P^T [q=32][kv=64], stride 72 u16 (144 B, 16B-aligned)
  u16* mysP = sP[wv];

  const u16* kbase = qkv + ((size_t)(b * SLEN)) * (3 * DMODEL) + DMODEL + h * DHEAD;
  const u16* vbase = vt + ((size_t)bh * DHEAD) * SLEN;
  const u16* qrow = qkv + ((size_t)(b * SLEN + qbase + col)) * (3 * DMODEL) + h * DHEAD;

  // Q fragments (used as MFMA B operand): [i=q-16block][ks]
  bf16x8 aQ[2][2];
#pragma unroll
  for (int i = 0; i < 2; ++i)
#pragma unroll
    for (int ks = 0; ks < 2; ++ks)
      aQ[i][ks] = *(const bf16x8*)(qrow + (size_t)i * 16 * (3 * DMODEL) + ks * 32 + quad * 8);

  f32x4 accO[2][4] = {}; // [i][j]: col=q(i-block), row=dh-within-16 (j-block)
  float m2[2] = {-1e30f, -1e30f}, l_i[2] = {0.0f, 0.0f}; // per-q stats (q = i*16+col)
  const float scl2 = 0.125f * 1.44269504088896f; // 1/sqrt(dh) * log2(e)

  for (int t = 0; t < ntiles; ++t) {
    const int kv0 = t * 64;

    // K fragments (A operand): rows kv, k=dh. Same addresses as before.
    bf16x8 bK[2][4]; // [ks][cb]
#pragma unroll
    for (int ks = 0; ks < 2; ++ks)
#pragma unroll
      for (int cb = 0; cb < 4; ++cb)
        bK[ks][cb] = *(const bf16x8*)(kbase + (size_t)(kv0 + cb * 16 + col) * (3 * DMODEL) +
                                      ks * 32 + quad * 8);
    // V^T fragments (A operand): rows dh, k=kv. Issued early (consumed after softmax).
    bf16x8 bV[2][4]; // [ks][j]
#pragma unroll
    for (int ks = 0; ks < 2; ++ks)
#pragma unroll
      for (int j = 0; j < 4; ++j)
        bV[ks][j] = *(const bf16x8*)(vbase + (size_t)(j * 16 + col) * SLEN + kv0 + ks * 32 + quad * 8);

    // S^T = K Q^T : accST[i][cb] col=q=i*16+col, row=kv=cb*16+quad*4+r (raw, unscaled)
    f32x4 accST[2][4] = {};
#pragma unroll
    for (int ks = 0; ks < 2; ++ks)
#pragma unroll
      for (int cb = 0; cb < 4; ++cb)
#pragma unroll
        for (int i = 0; i < 2; ++i)
          accST[i][cb] = __builtin_amdgcn_mfma_f32_16x16x32_bf16(bK[ks][cb], aQ[i][ks], accST[i][cb], 0, 0, 0);

    // causal mask on diagonal tile (raw domain)
    if (t == ntiles - 1) {
#pragma unroll
      for (int i = 0; i < 2; ++i) {
        int q = qbase + i * 16 + col;
#pragma unroll
        for (int cb = 0; cb < 4; ++cb) {
          int kvb = kv0 + cb * 16 + quad * 4;
#pragma unroll
          for (int r = 0; r < 4; ++r)
            if (kvb + r > q) accST[i][cb][r] = -1e30f;
        }
      }
    }

    // online softmax (exp2 domain). Row = q: 16 in-reg values + 2 shfl steps.
    float rmax[2], mnew[2], alpha[2], rsum[2];
#pragma unroll
    for (int i = 0; i < 2; ++i) {
      float m = accST[i][0][0];
#pragma unroll
      for (int cb = 0; cb < 4; ++cb)
#pragma unroll
        for (int r = 0; r < 4; ++r) m = fmaxf(m, accST[i][cb][r]);
      rmax[i] = m;
    }
#pragma unroll
    for (int i = 0; i < 2; ++i) {
      rmax[i] = fmaxf(rmax[i], __shfl_xor(rmax[i], 16));
      rmax[i] = fmaxf(rmax[i], __shfl_xor(rmax[i], 32));
      mnew[i] = fmaxf(m2[i], rmax[i] * scl2);
      alpha[i] = EXP2(m2[i] - mnew[i]);
      m2[i] = mnew[i];
    }
#pragma unroll
    for (int i = 0; i < 2; ++i) {
      float sacc = 0.0f;
#pragma unroll
      for (int cb = 0; cb < 4; ++cb)
#pragma unroll
        for (int r = 0; r < 4; ++r) {
          float p = EXP2(__builtin_fmaf(accST[i][cb][r], scl2, -mnew[i]));
          accST[i][cb][r] = p;
          sacc += p;
        }
      rsum[i] = sacc;
    }
#pragma unroll
    for (int i = 0; i < 2; ++i) {
      rsum[i] += __shfl_xor(rsum[i], 16);
      rsum[i] += __shfl_xor(rsum[i], 32);
      l_i[i] = l_i[i] * alpha[i] + rsum[i];
    }
#pragma unroll
    for (int i = 0; i < 2; ++i)
#pragma unroll
      for (int j = 0; j < 4; ++j)
#pragma unroll
        for (int r = 0; r < 4; ++r) accO[i][j][r] *= alpha[i];

    // P^T -> LDS [q][kv] packed: per (i,cb) one ds_write_b64 (kv-consecutive r)
#pragma unroll
    for (int i = 0; i < 2; ++i)
#pragma unroll
      for (int cb = 0; cb < 4; ++cb) {
        uint2 pk;
        pk.x = pack_trunc(accST[i][cb][0], accST[i][cb][1]);
        pk.y = pack_trunc(accST[i][cb][2], accST[i][cb][3]);
        *(uint2*)(mysP + (i * 16 + col) * 72 + cb * 16 + quad * 4) = pk;
      }
    // read P as B-frags: B[n=q][k=kv]
    bf16x8 aP[2][2];
#pragma unroll
    for (int i = 0; i < 2; ++i)
#pragma unroll
      for (int ks = 0; ks < 2; ++ks)
        aP[i][ks] = *(const bf16x8*)(mysP + (i * 16 + col) * 72 + ks * 32 + quad * 8);

    // O^T += V^T P^T
#pragma unroll
    for (int ks = 0; ks < 2; ++ks)
#pragma unroll
      for (int j = 0; j < 4; ++j)
#pragma unroll
        for (int i = 0; i < 2; ++i)
          accO[i][j] = __builtin_amdgcn_mfma_f32_16x16x32_bf16(bV[ks][j], aP[i][ks], accO[i][j], 0, 0, 0);
  }

  // epilogue: O^T col=q row=dh -> out[q][dh], packed dwordx2 stores
#pragma unroll
  for (int i = 0; i < 2; ++i) {
    float rl = 1.0f / l_i[i];
    size_t rowoff = ((size_t)(b * SLEN + qbase + i * 16 + col)) * DMODEL + h * DHEAD;
#pragma unroll
    for (int j = 0; j < 4; ++j) {
      uint2 pk;
      pk.x = pack_round(accO[i][j][0] * rl, accO[i][j][1] * rl);
      pk.y = pack_round(accO[i][j][2] * rl, accO[i][j][3] * rl);
      *(uint2*)(out + rowoff + j * 16 + quad * 4) = pk;
    }
  }
}

// ---------------- launch ----------------

extern "C" void kernel_launch(void* const* d_in, const int* in_sizes, int n_in,
                              void* d_out, int out_size, void* d_ws, size_t ws_size,
                              hipStream_t stream) {
  const float* x = (const float*)d_in[0];
  const float* Wq = (const float*)d_in[1];
  const float* bq = (const float*)d_in[2];
  const float* Wk = (const float*)d_in[3];
  const float* bk = (const float*)d_in[4];
  const float* Wv = (const float*)d_in[5];
  const float* bv = (const float*)d_in[6];
  const float* Wo = (const float*)d_in[7];
  const float* bo = (const float*)d_in[8];

  char* ws = (char*)d_ws;
  u16* xb = (u16*)ws;                              // 16 MB (reused as vt after QKV GEMM)
  u16* wqkvt = (u16*)(ws + ((size_t)16 << 20));    // 6 MB
  u16* wot = (u16*)(ws + ((size_t)22 << 20));      // 2 MB
  u16* qkv = (u16*)(ws + ((size_t)24 << 20));      // 48 MB
  u16* attnO = (u16*)(ws + ((size_t)72 << 20));    // 16 MB
  float* bqkv = (float*)(ws + ((size_t)88 << 20)); // 12 KB
  u16* vtp = xb;                                   // vt aliases xb (dead after QKV GEMM)

  convert_x_kernel<<<4096, 256, 0, stream>>>(x, xb);
  transpose_w_kernel<<<dim3(32, 32, 4), 256, 0, stream>>>(Wq, Wk, Wv, Wo, wqkvt, wot);
  concat_bias_kernel<<<12, 256, 0, stream>>>(bq, bk, bv, bqkv);
  gemm_bt_kernel<1><<<dim3(64, 24), 256, 0, stream>>>(xb, wqkvt, bqkv, (void*)qkv,
                                                      MROWS, 3 * DMODEL, DMODEL);
  transpose_v_kernel<<<dim3(64, 2, 64), 256, 0, stream>>>(qkv, vtp);
  attn_kernel<<<dim3(16, BATCH * NHEAD), 256, 0, stream>>>(qkv, vtp, attnO);
  gemm_bt_kernel<0><<<dim3(64, 8), 256, 0, stream>>>(attnO, wot, bo, d_out,
                                                     MROWS, DMODEL, DMODEL);
}

// Round 6
// 340.762 us; speedup vs baseline: 1.4489x; 1.4489x over previous
//
#include <hip/hip_runtime.h>

typedef unsigned short u16;
typedef unsigned int u32;
typedef __bf16 bf16x8 __attribute__((ext_vector_type(8)));
typedef float f32x4 __attribute__((ext_vector_type(4)));

#define BATCH 4
#define SLEN 2048
#define DMODEL 1024
#define NHEAD 16
#define DHEAD 64
#define MROWS (BATCH * SLEN) /* 8192 */

__device__ __forceinline__ u16 f32_to_bf16(float f) {
  u32 u = __float_as_uint(f);
  u32 r = (u + 0x7FFFu + ((u >> 16) & 1u)) >> 16;
  return (u16)r;
}
__device__ __forceinline__ u32 pack_bf16x2(float a, float b) {
  return (u32)f32_to_bf16(a) | ((u32)f32_to_bf16(b) << 16);
}

// pack two f32 -> two bf16 (truncate), 1 v_perm_b32
__device__ __forceinline__ u32 pack_trunc(float lo, float hi) {
#if __has_builtin(__builtin_amdgcn_perm)
  return __builtin_amdgcn_perm(__float_as_uint(hi), __float_as_uint(lo), 0x07060302u);
#else
  return (__float_as_uint(hi) & 0xFFFF0000u) | (__float_as_uint(lo) >> 16);
#endif
}
// pack with round-half-up (epilogue)
__device__ __forceinline__ u32 pack_round(float lo, float hi) {
  u32 ul = __float_as_uint(lo) + 0x8000u;
  u32 uh = __float_as_uint(hi) + 0x8000u;
#if __has_builtin(__builtin_amdgcn_perm)
  return __builtin_amdgcn_perm(uh, ul, 0x07060302u);
#else
  return (uh & 0xFFFF0000u) | (ul >> 16);
#endif
}

#if __has_builtin(__builtin_amdgcn_exp2f)
#define EXP2(x) __builtin_amdgcn_exp2f(x)
#else
#define EXP2(x) exp2f(x)
#endif

// async global->LDS, 16 B per lane; lds dest = wave-uniform base + lane*16
typedef const __attribute__((address_space(1))) void* gas_cv;
typedef __attribute__((address_space(3))) void* las_v;
__device__ __forceinline__ void async16(const u16* g, u16* l) {
  __builtin_amdgcn_global_load_lds((gas_cv)g, (las_v)l, 16, 0, 0);
}

// ---------------- prep kernels ----------------

__global__ void convert_x_kernel(const float* __restrict__ x, u16* __restrict__ xb) {
  size_t i = ((size_t)blockIdx.x * 256 + threadIdx.x) * 8;
  float4 v0 = *(const float4*)(x + i);
  float4 v1 = *(const float4*)(x + i + 4);
  uint4 o;
  o.x = pack_bf16x2(v0.x, v0.y);
  o.y = pack_bf16x2(v0.z, v0.w);
  o.z = pack_bf16x2(v1.x, v1.y);
  o.w = pack_bf16x2(v1.z, v1.w);
  *(uint4*)(xb + i) = o;
}

__global__ void transpose_w_kernel(const float* __restrict__ Wq, const float* __restrict__ Wk,
                                   const float* __restrict__ Wv, const float* __restrict__ Wo,
                                   u16* __restrict__ wqkvt, u16* __restrict__ wot) {
  __shared__ float tile[32][33];
  int z = blockIdx.z;
  const float* src = (z == 0) ? Wq : (z == 1) ? Wk : (z == 2) ? Wv : Wo;
  u16* dst = (z < 3) ? (wqkvt + (size_t)z * DMODEL * DMODEL) : wot;
  int c0 = blockIdx.x * 32, r0 = blockIdx.y * 32;
  int tx = threadIdx.x & 31, ty = threadIdx.x >> 5;
#pragma unroll
  for (int i = 0; i < 4; ++i)
    tile[ty + 8 * i][tx] = src[(size_t)(r0 + ty + 8 * i) * DMODEL + c0 + tx];
  __syncthreads();
#pragma unroll
  for (int i = 0; i < 4; ++i)
    dst[(size_t)(c0 + ty + 8 * i) * DMODEL + r0 + tx] = f32_to_bf16(tile[tx][ty + 8 * i]);
}

__global__ void concat_bias_kernel(const float* __restrict__ bq, const float* __restrict__ bk,
                                   const float* __restrict__ bv, float* __restrict__ bqkv) {
  int i = blockIdx.x * 256 + threadIdx.x;
  float v = (i < 1024) ? bq[i] : (i < 2048) ? bk[i - 1024] : bv[i - 2048];
  bqkv[i] = v;
}

// V slice of qkv [b][s][h*64+dh] -> vt [b][h][dh][s]
__global__ void transpose_v_kernel(const u16* __restrict__ qkv, u16* __restrict__ vt) {
  __shared__ u16 tile[32][33];
  const int bh = blockIdx.z;
  const int b = bh >> 4, h = bh & 15;
  const int s0 = blockIdx.x * 32, d0 = blockIdx.y * 32;
  const int tx = threadIdx.x & 31, ty = threadIdx.x >> 5;
#pragma unroll
  for (int i = 0; i < 4; ++i)
    tile[ty + 8 * i][tx] =
        qkv[(size_t)(b * SLEN + s0 + ty + 8 * i) * (3 * DMODEL) + 2 * DMODEL + h * DHEAD + d0 + tx];
  __syncthreads();
#pragma unroll
  for (int i = 0; i < 4; ++i)
    vt[(size_t)(bh * DHEAD + d0 + ty + 8 * i) * SLEN + s0 + tx] = tile[tx][ty + 8 * i];
}

// ---------------- GEMM with global_load_lds (m97 pattern, unchanged) ----------------
template <int OUT_BF16>
__global__ __launch_bounds__(256) void gemm_bt_kernel(const u16* __restrict__ A,
                                                      const u16* __restrict__ Bt,
                                                      const float* __restrict__ bias,
                                                      void* __restrict__ Cout,
                                                      int M, int N, int K) {
  __shared__ u16 sA[128 * 32];
  __shared__ u16 sB[128 * 32];
  const int tid = threadIdx.x;
  const int wv = tid >> 6, lane = tid & 63;
  const int wr = wv >> 1, wc = wv & 1;
  const int col = lane & 15, quad = lane >> 4;
  const int m0 = blockIdx.x * 128;
  const int n0 = blockIdx.y * 128;

  f32x4 acc[4][4] = {};

  const int lr = tid >> 2;
  const int ls = tid & 3;
  const size_t a_base = (size_t)(m0 + lr) * K + ls * 8;
  const size_t b_base = (size_t)(n0 + lr) * K + ls * 8;
  u16* ldsA0 = sA + ((tid >> 6) << 9);
  u16* ldsA1 = ldsA0 + 2048;
  u16* ldsB0 = sB + ((tid >> 6) << 9);
  u16* ldsB1 = ldsB0 + 2048;

  for (int k0 = 0; k0 < K; k0 += 32) {
    async16(A + a_base + k0, ldsA0);
    async16(A + a_base + (size_t)64 * K + k0, ldsA1);
    async16(Bt + b_base + k0, ldsB0);
    async16(Bt + b_base + (size_t)64 * K + k0, ldsB1);
    __syncthreads();
    bf16x8 af[4], bfr[4];
#pragma unroll
    for (int i = 0; i < 4; ++i)
      af[i] = *(const bf16x8*)(sA + (wr * 64 + i * 16 + col) * 32 + quad * 8);
#pragma unroll
    for (int j = 0; j < 4; ++j)
      bfr[j] = *(const bf16x8*)(sB + (wc * 64 + j * 16 + col) * 32 + quad * 8);
#pragma unroll
    for (int i = 0; i < 4; ++i)
#pragma unroll
      for (int j = 0; j < 4; ++j)
        acc[i][j] = __builtin_amdgcn_mfma_f32_16x16x32_bf16(af[i], bfr[j], acc[i][j], 0, 0, 0);
    __syncthreads();
  }

#pragma unroll
  for (int i = 0; i < 4; ++i) {
#pragma unroll
    for (int j = 0; j < 4; ++j) {
      int n = n0 + wc * 64 + j * 16 + col;
      float bia = bias[n];
#pragma unroll
      for (int r = 0; r < 4; ++r) {
        int m = m0 + wr * 64 + i * 16 + quad * 4 + r;
        float v = acc[i][j][r] + bia;
        if (OUT_BF16)
          ((u16*)Cout)[(size_t)m * N + n] = f32_to_bf16(v);
        else
          ((float*)Cout)[(size_t)m * N + n] = v;
      }
    }
  }
}

// ---------------- flash attention v4: R4 structure + R5 math ----------------
// grid (8, BATCH*NHEAD), 256 thr = 4 waves. Wave handles paired strips s and 63-s
// (32 q-rows each) -> uniform 33 kv-tiles/wave, no drain tail. No __syncthreads.
// K and V fragments double-buffered in registers (prefetch next tile during compute).
// S^T = mfma(K,Q): softmax reduce = in-reg fmax + 2 shfl; exp2-domain; packed P/O.
__global__ __launch_bounds__(256, 2) void attn_kernel(const u16* __restrict__ qkv,
                                                      const u16* __restrict__ vt,
                                                      u16* __restrict__ out) {
  const int bh = blockIdx.y;
  const int b = bh >> 4, h = bh & 15;
  const int tid = threadIdx.x;
  const int wv = tid >> 6, lane = tid & 63;
  const int col = lane & 15, quad = lane >> 4;
  const int sfirst = blockIdx.x * 4 + wv; // 0..31

  __shared__ u16 sP[4][32 * 72]; // per-wave P^T, stride 72 u16
  u16* mysP = sP[wv];

  const u16* kbase = qkv + ((size_t)(b * SLEN)) * (3 * DMODEL) + DMODEL + h * DHEAD;
  const u16* vbase = vt + ((size_t)bh * DHEAD) * SLEN;
  const float scl2 = 0.125f * 1.44269504088896f; // 1/sqrt(dh) * log2(e)

  for (int half = 0; half < 2; ++half) {
    const int s2 = half ? (63 - sfirst) : sfirst;
    const int qbase = s2 * 32;
    const int ntiles = s2 / 2 + 1;

    const u16* qrow = qkv + ((size_t)(b * SLEN + qbase + col)) * (3 * DMODEL) + h * DHEAD;
    bf16x8 aQ[2][2]; // Q as MFMA B operand: [i=q-16block][ks]
#pragma unroll
    for (int i = 0; i < 2; ++i)
#pragma unroll
      for (int ks = 0; ks < 2; ++ks)
        aQ[i][ks] = *(const bf16x8*)(qrow + (size_t)i * 16 * (3 * DMODEL) + ks * 32 + quad * 8);

    f32x4 accO[2][4] = {}; // [i][j]: col=q, rows=dh
    float m2[2] = {-1e30f, -1e30f}, l_i[2] = {0.0f, 0.0f};

    // prologue: tile-0 K and V fragments
    bf16x8 bKc[2][4], bKn[2][4], bVc[2][4], bVn[2][4];
#pragma unroll
    for (int ks = 0; ks < 2; ++ks)
#pragma unroll
      for (int cb = 0; cb < 4; ++cb)
        bKc[ks][cb] =
            *(const bf16x8*)(kbase + (size_t)(cb * 16 + col) * (3 * DMODEL) + ks * 32 + quad * 8);
#pragma unroll
    for (int ks = 0; ks < 2; ++ks)
#pragma unroll
      for (int j = 0; j < 4; ++j)
        bVc[ks][j] = *(const bf16x8*)(vbase + (size_t)(j * 16 + col) * SLEN + ks * 32 + quad * 8);

    for (int t = 0; t < ntiles; ++t) {
      const int kv0 = t * 64;
      const int kvn = (t + 1 < ntiles) ? kv0 + 64 : kv0;

      // prefetch next tile's K and V fragments (consumed next iteration)
#pragma unroll
      for (int ks = 0; ks < 2; ++ks)
#pragma unroll
        for (int cb = 0; cb < 4; ++cb)
          bKn[ks][cb] = *(const bf16x8*)(kbase + (size_t)(kvn + cb * 16 + col) * (3 * DMODEL) +
                                         ks * 32 + quad * 8);
#pragma unroll
      for (int ks = 0; ks < 2; ++ks)
#pragma unroll
        for (int j = 0; j < 4; ++j)
          bVn[ks][j] =
              *(const bf16x8*)(vbase + (size_t)(j * 16 + col) * SLEN + kvn + ks * 32 + quad * 8);

      // S^T = K Q^T : accST[i][cb] col=q=i*16+col, row=kv=cb*16+quad*4+r (raw)
      f32x4 accST[2][4] = {};
#pragma unroll
      for (int ks = 0; ks < 2; ++ks)
#pragma unroll
        for (int cb = 0; cb < 4; ++cb)
#pragma unroll
          for (int i = 0; i < 2; ++i)
            accST[i][cb] =
                __builtin_amdgcn_mfma_f32_16x16x32_bf16(bKc[ks][cb], aQ[i][ks], accST[i][cb], 0, 0, 0);

      // causal mask on diagonal tile (raw domain)
      if (t == ntiles - 1) {
#pragma unroll
        for (int i = 0; i < 2; ++i) {
          int q = qbase + i * 16 + col;
#pragma unroll
          for (int cb = 0; cb < 4; ++cb) {
            int kvb = kv0 + cb * 16 + quad * 4;
#pragma unroll
            for (int r = 0; r < 4; ++r)
              if (kvb + r > q) accST[i][cb][r] = -1e30f;
          }
        }
      }

      // online softmax (exp2 domain): 16 in-reg fmax + 2 shfl per i-block
      float rmax[2], mnew[2], alpha[2], rsum[2];
#pragma unroll
      for (int i = 0; i < 2; ++i) {
        float m = accST[i][0][0];
#pragma unroll
        for (int cb = 0; cb < 4; ++cb)
#pragma unroll
          for (int r = 0; r < 4; ++r) m = fmaxf(m, accST[i][cb][r]);
        rmax[i] = m;
      }
#pragma unroll
      for (int i = 0; i < 2; ++i) {
        rmax[i] = fmaxf(rmax[i], __shfl_xor(rmax[i], 16));
        rmax[i] = fmaxf(rmax[i], __shfl_xor(rmax[i], 32));
        mnew[i] = fmaxf(m2[i], rmax[i] * scl2);
        alpha[i] = EXP2(m2[i] - mnew[i]);
        m2[i] = mnew[i];
      }
#pragma unroll
      for (int i = 0; i < 2; ++i) {
        float sacc = 0.0f;
#pragma unroll
        for (int cb = 0; cb < 4; ++cb)
#pragma unroll
          for (int r = 0; r < 4; ++r) {
            float p = EXP2(__builtin_fmaf(accST[i][cb][r], scl2, -mnew[i]));
            accST[i][cb][r] = p;
            sacc += p;
          }
        rsum[i] = sacc;
      }
#pragma unroll
      for (int i = 0; i < 2; ++i) {
        rsum[i] += __shfl_xor(rsum[i], 16);
        rsum[i] += __shfl_xor(rsum[i], 32);
        l_i[i] = l_i[i] * alpha[i] + rsum[i];
      }
#pragma unroll
      for (int i = 0; i < 2; ++i)
#pragma unroll
        for (int j = 0; j < 4; ++j)
#pragma unroll
          for (int r = 0; r < 4; ++r) accO[i][j][r] *= alpha[i];

      // P^T -> LDS packed (b64 per (i,cb)), then read as B-frags (intra-wave)
#pragma unroll
      for (int i = 0; i < 2; ++i)
#pragma unroll
        for (int cb = 0; cb < 4; ++cb) {
          uint2 pk;
          pk.x = pack_trunc(accST[i][cb][0], accST[i][cb][1]);
          pk.y = pack_trunc(accST[i][cb][2], accST[i][cb][3]);
          *(uint2*)(mysP + (i * 16 + col) * 72 + cb * 16 + quad * 4) = pk;
        }
      bf16x8 aP[2][2];
#pragma unroll
      for (int i = 0; i < 2; ++i)
#pragma unroll
        for (int ks = 0; ks < 2; ++ks)
          aP[i][ks] = *(const bf16x8*)(mysP + (i * 16 + col) * 72 + ks * 32 + quad * 8);

      // O^T += V^T P^T
#pragma unroll
      for (int ks = 0; ks < 2; ++ks)
#pragma unroll
        for (int j = 0; j < 4; ++j)
#pragma unroll
          for (int i = 0; i < 2; ++i)
            accO[i][j] =
                __builtin_amdgcn_mfma_f32_16x16x32_bf16(bVc[ks][j], aP[i][ks], accO[i][j], 0, 0, 0);

      // rotate double-buffers
#pragma unroll
      for (int ks = 0; ks < 2; ++ks)
#pragma unroll
        for (int cb = 0; cb < 4; ++cb) {
          bKc[ks][cb] = bKn[ks][cb];
          bVc[ks][cb] = bVn[ks][cb];
        }
    }

    // epilogue: O^T col=q row=dh -> out[q][dh], packed dwordx2 stores
#pragma unroll
    for (int i = 0; i < 2; ++i) {
      float rl = 1.0f / l_i[i];
      size_t rowoff = ((size_t)(b * SLEN + qbase + i * 16 + col)) * DMODEL + h * DHEAD;
#pragma unroll
      for (int j = 0; j < 4; ++j) {
        uint2 pk;
        pk.x = pack_round(accO[i][j][0] * rl, accO[i][j][1] * rl);
        pk.y = pack_round(accO[i][j][2] * rl, accO[i][j][3] * rl);
        *(uint2*)(out + rowoff + j * 16 + quad * 4) = pk;
      }
    }
  }
}

// ---------------- launch ----------------

extern "C" void kernel_launch(void* const* d_in, const int* in_sizes, int n_in,
                              void* d_out, int out_size, void* d_ws, size_t ws_size,
                              hipStream_t stream) {
  const float* x = (const float*)d_in[0];
  const float* Wq = (const float*)d_in[1];
  const float* bq = (const float*)d_in[2];
  const float* Wk = (const float*)d_in[3];
  const float* bk = (const float*)d_in[4];
  const float* Wv = (const float*)d_in[5];
  const float* bv = (const float*)d_in[6];
  const float* Wo = (const float*)d_in[7];
  const float* bo = (const float*)d_in[8];

  char* ws = (char*)d_ws;
  u16* xb = (u16*)ws;                              // 16 MB (reused as vt after QKV GEMM)
  u16* wqkvt = (u16*)(ws + ((size_t)16 << 20));    // 6 MB
  u16* wot = (u16*)(ws + ((size_t)22 << 20));      // 2 MB
  u16* qkv = (u16*)(ws + ((size_t)24 << 20));      // 48 MB
  u16* attnO = (u16*)(ws + ((size_t)72 << 20));    // 16 MB
  float* bqkv = (float*)(ws + ((size_t)88 << 20)); // 12 KB
  u16* vtp = xb;                                   // vt aliases xb (dead after QKV GEMM)

  convert_x_kernel<<<4096, 256, 0, stream>>>(x, xb);
  transpose_w_kernel<<<dim3(32, 32, 4), 256, 0, stream>>>(Wq, Wk, Wv, Wo, wqkvt, wot);
  concat_bias_kernel<<<12, 256, 0, stream>>>(bq, bk, bv, bqkv);
  gemm_bt_kernel<1><<<dim3(64, 24), 256, 0, stream>>>(xb, wqkvt, bqkv, (void*)qkv,
                                                      MROWS, 3 * DMODEL, DMODEL);
  transpose_v_kernel<<<dim3(64, 2, 64), 256, 0, stream>>>(qkv, vtp);
  attn_kernel<<<dim3(8, BATCH * NHEAD), 256, 0, stream>>>(qkv, vtp, attnO);
  gemm_bt_kernel<0><<<dim3(64, 8), 256, 0, stream>>>(attnO, wot, bo, d_out,
                                                     MROWS, DMODEL, DMODEL);
}

// Round 7
// 286.321 us; speedup vs baseline: 1.7244x; 1.1901x over previous
//
#include <hip/hip_runtime.h>

typedef unsigned short u16;
typedef unsigned int u32;
typedef __bf16 bf16x8 __attribute__((ext_vector_type(8)));
typedef float f32x4 __attribute__((ext_vector_type(4)));

#define BATCH 4
#define SLEN 2048
#define DMODEL 1024
#define NHEAD 16
#define DHEAD 64
#define MROWS (BATCH * SLEN) /* 8192 */

__device__ __forceinline__ u16 f32_to_bf16(float f) {
  u32 u = __float_as_uint(f);
  u32 r = (u + 0x7FFFu + ((u >> 16) & 1u)) >> 16;
  return (u16)r;
}
__device__ __forceinline__ u32 pack_bf16x2(float a, float b) {
  return (u32)f32_to_bf16(a) | ((u32)f32_to_bf16(b) << 16);
}

// pack two f32 -> two bf16 (truncate), 1 v_perm_b32
__device__ __forceinline__ u32 pack_trunc(float lo, float hi) {
#if __has_builtin(__builtin_amdgcn_perm)
  return __builtin_amdgcn_perm(__float_as_uint(hi), __float_as_uint(lo), 0x07060302u);
#else
  return (__float_as_uint(hi) & 0xFFFF0000u) | (__float_as_uint(lo) >> 16);
#endif
}
// pack with round-half-up (epilogue)
__device__ __forceinline__ u32 pack_round(float lo, float hi) {
  u32 ul = __float_as_uint(lo) + 0x8000u;
  u32 uh = __float_as_uint(hi) + 0x8000u;
#if __has_builtin(__builtin_amdgcn_perm)
  return __builtin_amdgcn_perm(uh, ul, 0x07060302u);
#else
  return (uh & 0xFFFF0000u) | (ul >> 16);
#endif
}

#if __has_builtin(__builtin_amdgcn_exp2f)
#define EXP2(x) __builtin_amdgcn_exp2f(x)
#else
#define EXP2(x) exp2f(x)
#endif

// async global->LDS, 16 B per lane; lds dest = wave-uniform base + lane*16
typedef const __attribute__((address_space(1))) void* gas_cv;
typedef __attribute__((address_space(3))) void* las_v;
__device__ __forceinline__ void async16(const u16* g, u16* l) {
  __builtin_amdgcn_global_load_lds((gas_cv)g, (las_v)l, 16, 0, 0);
}

// ---------------- prep kernels ----------------

__global__ void convert_x_kernel(const float* __restrict__ x, u16* __restrict__ xb) {
  size_t i = ((size_t)blockIdx.x * 256 + threadIdx.x) * 8;
  float4 v0 = *(const float4*)(x + i);
  float4 v1 = *(const float4*)(x + i + 4);
  uint4 o;
  o.x = pack_bf16x2(v0.x, v0.y);
  o.y = pack_bf16x2(v0.z, v0.w);
  o.z = pack_bf16x2(v1.x, v1.y);
  o.w = pack_bf16x2(v1.z, v1.w);
  *(uint4*)(xb + i) = o;
}

__global__ void transpose_w_kernel(const float* __restrict__ Wq, const float* __restrict__ Wk,
                                   const float* __restrict__ Wv, const float* __restrict__ Wo,
                                   u16* __restrict__ wqkvt, u16* __restrict__ wot) {
  __shared__ float tile[32][33];
  int z = blockIdx.z;
  const float* src = (z == 0) ? Wq : (z == 1) ? Wk : (z == 2) ? Wv : Wo;
  u16* dst = (z < 3) ? (wqkvt + (size_t)z * DMODEL * DMODEL) : wot;
  int c0 = blockIdx.x * 32, r0 = blockIdx.y * 32;
  int tx = threadIdx.x & 31, ty = threadIdx.x >> 5;
#pragma unroll
  for (int i = 0; i < 4; ++i)
    tile[ty + 8 * i][tx] = src[(size_t)(r0 + ty + 8 * i) * DMODEL + c0 + tx];
  __syncthreads();
#pragma unroll
  for (int i = 0; i < 4; ++i)
    dst[(size_t)(c0 + ty + 8 * i) * DMODEL + r0 + tx] = f32_to_bf16(tile[tx][ty + 8 * i]);
}

__global__ void concat_bias_kernel(const float* __restrict__ bq, const float* __restrict__ bk,
                                   const float* __restrict__ bv, float* __restrict__ bqkv) {
  int i = blockIdx.x * 256 + threadIdx.x;
  float v = (i < 1024) ? bq[i] : (i < 2048) ? bk[i - 1024] : bv[i - 2048];
  bqkv[i] = v;
}

// V slice of qkv [b][s][h*64+dh] -> vt [b][h][dh][s]
__global__ void transpose_v_kernel(const u16* __restrict__ qkv, u16* __restrict__ vt) {
  __shared__ u16 tile[32][33];
  const int bh = blockIdx.z;
  const int b = bh >> 4, h = bh & 15;
  const int s0 = blockIdx.x * 32, d0 = blockIdx.y * 32;
  const int tx = threadIdx.x & 31, ty = threadIdx.x >> 5;
#pragma unroll
  for (int i = 0; i < 4; ++i)
    tile[ty + 8 * i][tx] =
        qkv[(size_t)(b * SLEN + s0 + ty + 8 * i) * (3 * DMODEL) + 2 * DMODEL + h * DHEAD + d0 + tx];
  __syncthreads();
#pragma unroll
  for (int i = 0; i < 4; ++i)
    vt[(size_t)(bh * DHEAD + d0 + ty + 8 * i) * SLEN + s0 + tx] = tile[tx][ty + 8 * i];
}

// ---------------- GEMM with global_load_lds (m97 pattern, unchanged) ----------------
template <int OUT_BF16>
__global__ __launch_bounds__(256) void gemm_bt_kernel(const u16* __restrict__ A,
                                                      const u16* __restrict__ Bt,
                                                      const float* __restrict__ bias,
                                                      void* __restrict__ Cout,
                                                      int M, int N, int K) {
  __shared__ u16 sA[128 * 32];
  __shared__ u16 sB[128 * 32];
  const int tid = threadIdx.x;
  const int wv = tid >> 6, lane = tid & 63;
  const int wr = wv >> 1, wc = wv & 1;
  const int col = lane & 15, quad = lane >> 4;
  const int m0 = blockIdx.x * 128;
  const int n0 = blockIdx.y * 128;

  f32x4 acc[4][4] = {};

  const int lr = tid >> 2;
  const int ls = tid & 3;
  const size_t a_base = (size_t)(m0 + lr) * K + ls * 8;
  const size_t b_base = (size_t)(n0 + lr) * K + ls * 8;
  u16* ldsA0 = sA + ((tid >> 6) << 9);
  u16* ldsA1 = ldsA0 + 2048;
  u16* ldsB0 = sB + ((tid >> 6) << 9);
  u16* ldsB1 = ldsB0 + 2048;

  for (int k0 = 0; k0 < K; k0 += 32) {
    async16(A + a_base + k0, ldsA0);
    async16(A + a_base + (size_t)64 * K + k0, ldsA1);
    async16(Bt + b_base + k0, ldsB0);
    async16(Bt + b_base + (size_t)64 * K + k0, ldsB1);
    __syncthreads();
    bf16x8 af[4], bfr[4];
#pragma unroll
    for (int i = 0; i < 4; ++i)
      af[i] = *(const bf16x8*)(sA + (wr * 64 + i * 16 + col) * 32 + quad * 8);
#pragma unroll
    for (int j = 0; j < 4; ++j)
      bfr[j] = *(const bf16x8*)(sB + (wc * 64 + j * 16 + col) * 32 + quad * 8);
#pragma unroll
    for (int i = 0; i < 4; ++i)
#pragma unroll
      for (int j = 0; j < 4; ++j)
        acc[i][j] = __builtin_amdgcn_mfma_f32_16x16x32_bf16(af[i], bfr[j], acc[i][j], 0, 0, 0);
    __syncthreads();
  }

#pragma unroll
  for (int i = 0; i < 4; ++i) {
#pragma unroll
    for (int j = 0; j < 4; ++j) {
      int n = n0 + wc * 64 + j * 16 + col;
      float bia = bias[n];
#pragma unroll
      for (int r = 0; r < 4; ++r) {
        int m = m0 + wr * 64 + i * 16 + quad * 4 + r;
        float v = acc[i][j][r] + bia;
        if (OUT_BF16)
          ((u16*)Cout)[(size_t)m * N + n] = f32_to_bf16(v);
        else
          ((float*)Cout)[(size_t)m * N + n] = v;
      }
    }
  }
}

// ---------------- flash attention v5: cooperative LDS K/V staging ----------------
// grid (8, BATCH*NHEAD), 256 thr = 4 waves. Wave wv owns paired strips s=bx*4+wv and
// 63-s (32 q-rows each). All 4 waves share kv-tile t -> block stages K/V tile ONCE into
// double-buffered LDS via global_load_lds (prefetch 1 tile ahead), 1 barrier/tile.
// Every block runs exactly 34 tile-iterations (uniform duration).
// LDS K/V layout [row][64] with XOR(row&7) swizzle on 16B segs (applied on the global
// side of the async copy) -> ds_read_b128 phases spread across all 8 bank groups.
__global__ __launch_bounds__(256, 2) void attn_kernel(const u16* __restrict__ qkv,
                                                      const u16* __restrict__ vt,
                                                      u16* __restrict__ out) {
  const int bh = blockIdx.y;
  const int b = bh >> 4, h = bh & 15;
  const int tid = threadIdx.x;
  const int wv = tid >> 6, lane = tid & 63;
  const int col = lane & 15, quad = lane >> 4;
  const int bx = blockIdx.x;
  const int sfirst = bx * 4 + wv; // 0..31

  __shared__ u16 sK[2][64 * 64];
  __shared__ u16 sV[2][64 * 64];
  __shared__ u16 sP[4][32 * 72];
  u16* mysP = sP[wv];

  const u16* kbase = qkv + ((size_t)(b * SLEN)) * (3 * DMODEL) + DMODEL + h * DHEAD;
  const u16* vbase = vt + ((size_t)bh * DHEAD) * SLEN;
  const float scl2 = 0.125f * 1.44269504088896f; // 1/sqrt(dh) * log2(e)

  // staging mapping: each wave stages rows [wv*16, wv*16+16) of both tiles (2 calls each).
  // lane -> (lrow = lane>>3, lseg = lane&7); global seg fetched = lseg ^ lrow (row&7 == lrow).
  const int lrow = lane >> 3;
  const int sga = (lane & 7) ^ lrow; // swizzled global seg
  const int r0a = wv * 16, r0b = wv * 16 + 8;
  const int swz = ((quad /*ks=0*/) ^ (col & 7)) * 8; // reader base swizzle for ks=0; ks=1 adds 32^...

  for (int half = 0; half < 2; ++half) {
    const int s2 = half ? (63 - sfirst) : sfirst;
    const int qbase = s2 * 32;
    const int nt_own = s2 / 2 + 1;
    const int nt_max = half ? (32 - 2 * bx) : (2 * bx + 2); // block-uniform

    const u16* qrow = qkv + ((size_t)(b * SLEN + qbase + col)) * (3 * DMODEL) + h * DHEAD;
    bf16x8 aQ[2][2]; // Q as MFMA B operand: [i=q-16block][ks]
#pragma unroll
    for (int i = 0; i < 2; ++i)
#pragma unroll
      for (int ks = 0; ks < 2; ++ks)
        aQ[i][ks] = *(const bf16x8*)(qrow + (size_t)i * 16 * (3 * DMODEL) + ks * 32 + quad * 8);

    f32x4 accO[2][4] = {}; // [i][j]: col=q, rows=dh
    float m2[2] = {-1e30f, -1e30f}, l_i[2] = {0.0f, 0.0f};

    // prologue: stage tile 0 into buffer 0
    async16(kbase + (size_t)(r0a + lrow) * (3 * DMODEL) + sga * 8, sK[0] + r0a * 64);
    async16(kbase + (size_t)(r0b + lrow) * (3 * DMODEL) + sga * 8, sK[0] + r0b * 64);
    async16(vbase + (size_t)(r0a + lrow) * SLEN + sga * 8, sV[0] + r0a * 64);
    async16(vbase + (size_t)(r0b + lrow) * SLEN + sga * 8, sV[0] + r0b * 64);
    __syncthreads();

    for (int t = 0; t < nt_max; ++t) {
      const int kv0 = t * 64;
      const int cur = t & 1, nxt = cur ^ 1;

      // prefetch next tile into the other buffer (drained by this iteration's end barrier)
      if (t + 1 < nt_max) {
        const int kvn = kv0 + 64;
        async16(kbase + (size_t)(kvn + r0a + lrow) * (3 * DMODEL) + sga * 8, sK[nxt] + r0a * 64);
        async16(kbase + (size_t)(kvn + r0b + lrow) * (3 * DMODEL) + sga * 8, sK[nxt] + r0b * 64);
        async16(vbase + (size_t)(r0a + lrow) * SLEN + kvn + sga * 8, sV[nxt] + r0a * 64);
        async16(vbase + (size_t)(r0b + lrow) * SLEN + kvn + sga * 8, sV[nxt] + r0b * 64);
      }

      if (t < nt_own) {
        const u16* sKc = sK[cur];
        const u16* sVc = sV[cur];
        // fragments from LDS (swizzled addressing)
        bf16x8 bK[2][4], bV[2][4];
#pragma unroll
        for (int ks = 0; ks < 2; ++ks) {
          const int sl = (((ks * 4 + quad) ^ (col & 7)) * 8);
#pragma unroll
          for (int cb = 0; cb < 4; ++cb)
            bK[ks][cb] = *(const bf16x8*)(sKc + (cb * 16 + col) * 64 + sl);
#pragma unroll
          for (int j = 0; j < 4; ++j)
            bV[ks][j] = *(const bf16x8*)(sVc + (j * 16 + col) * 64 + sl);
        }

        // S^T = K Q^T : accST[i][cb] col=q=i*16+col, row=kv=cb*16+quad*4+r (raw)
        f32x4 accST[2][4] = {};
#pragma unroll
        for (int ks = 0; ks < 2; ++ks)
#pragma unroll
          for (int cb = 0; cb < 4; ++cb)
#pragma unroll
            for (int i = 0; i < 2; ++i)
              accST[i][cb] = __builtin_amdgcn_mfma_f32_16x16x32_bf16(bK[ks][cb], aQ[i][ks],
                                                                    accST[i][cb], 0, 0, 0);

        // causal mask on diagonal tile (raw domain)
        if (t == nt_own - 1) {
#pragma unroll
          for (int i = 0; i < 2; ++i) {
            int q = qbase + i * 16 + col;
#pragma unroll
            for (int cb = 0; cb < 4; ++cb) {
              int kvb = kv0 + cb * 16 + quad * 4;
#pragma unroll
              for (int r = 0; r < 4; ++r)
                if (kvb + r > q) accST[i][cb][r] = -1e30f;
            }
          }
        }

        // online softmax (exp2 domain): in-reg fmax + 2 shfl per i-block
        float rmax[2], mnew[2], alpha[2], rsum[2];
#pragma unroll
        for (int i = 0; i < 2; ++i) {
          float m = accST[i][0][0];
#pragma unroll
          for (int cb = 0; cb < 4; ++cb)
#pragma unroll
            for (int r = 0; r < 4; ++r) m = fmaxf(m, accST[i][cb][r]);
          rmax[i] = m;
        }
#pragma unroll
        for (int i = 0; i < 2; ++i) {
          rmax[i] = fmaxf(rmax[i], __shfl_xor(rmax[i], 16));
          rmax[i] = fmaxf(rmax[i], __shfl_xor(rmax[i], 32));
          mnew[i] = fmaxf(m2[i], rmax[i] * scl2);
          alpha[i] = EXP2(m2[i] - mnew[i]);
          m2[i] = mnew[i];
        }
#pragma unroll
        for (int i = 0; i < 2; ++i) {
          float sacc = 0.0f;
#pragma unroll
          for (int cb = 0; cb < 4; ++cb)
#pragma unroll
            for (int r = 0; r < 4; ++r) {
              float p = EXP2(__builtin_fmaf(accST[i][cb][r], scl2, -mnew[i]));
              accST[i][cb][r] = p;
              sacc += p;
            }
          rsum[i] = sacc;
        }
#pragma unroll
        for (int i = 0; i < 2; ++i) {
          rsum[i] += __shfl_xor(rsum[i], 16);
          rsum[i] += __shfl_xor(rsum[i], 32);
          l_i[i] = l_i[i] * alpha[i] + rsum[i];
        }
#pragma unroll
        for (int i = 0; i < 2; ++i)
#pragma unroll
          for (int j = 0; j < 4; ++j)
#pragma unroll
            for (int r = 0; r < 4; ++r) accO[i][j][r] *= alpha[i];

        // P^T -> per-wave LDS packed (b64 per (i,cb)), read back as B-frags (intra-wave)
#pragma unroll
        for (int i = 0; i < 2; ++i)
#pragma unroll
          for (int cb = 0; cb < 4; ++cb) {
            uint2 pk;
            pk.x = pack_trunc(accST[i][cb][0], accST[i][cb][1]);
            pk.y = pack_trunc(accST[i][cb][2], accST[i][cb][3]);
            *(uint2*)(mysP + (i * 16 + col) * 72 + cb * 16 + quad * 4) = pk;
          }
        bf16x8 aP[2][2];
#pragma unroll
        for (int i = 0; i < 2; ++i)
#pragma unroll
          for (int ks = 0; ks < 2; ++ks)
            aP[i][ks] = *(const bf16x8*)(mysP + (i * 16 + col) * 72 + ks * 32 + quad * 8);

        // O^T += V^T P^T
#pragma unroll
        for (int ks = 0; ks < 2; ++ks)
#pragma unroll
          for (int j = 0; j < 4; ++j)
#pragma unroll
            for (int i = 0; i < 2; ++i)
              accO[i][j] = __builtin_amdgcn_mfma_f32_16x16x32_bf16(bV[ks][j], aP[i][ks],
                                                                  accO[i][j], 0, 0, 0);
      }

      __syncthreads(); // all waves done reading cur; drains prefetch into nxt
    }

    // epilogue: O^T col=q row=dh -> out[q][dh], packed dwordx2 stores
#pragma unroll
    for (int i = 0; i < 2; ++i) {
      float rl = 1.0f / l_i[i];
      size_t rowoff = ((size_t)(b * SLEN + qbase + i * 16 + col)) * DMODEL + h * DHEAD;
#pragma unroll
      for (int j = 0; j < 4; ++j) {
        uint2 pk;
        pk.x = pack_round(accO[i][j][0] * rl, accO[i][j][1] * rl);
        pk.y = pack_round(accO[i][j][2] * rl, accO[i][j][3] * rl);
        *(uint2*)(out + rowoff + j * 16 + quad * 4) = pk;
      }
    }
  }
}

// ---------------- launch ----------------

extern "C" void kernel_launch(void* const* d_in, const int* in_sizes, int n_in,
                              void* d_out, int out_size, void* d_ws, size_t ws_size,
                              hipStream_t stream) {
  const float* x = (const float*)d_in[0];
  const float* Wq = (const float*)d_in[1];
  const float* bq = (const float*)d_in[2];
  const float* Wk = (const float*)d_in[3];
  const float* bk = (const float*)d_in[4];
  const float* Wv = (const float*)d_in[5];
  const float* bv = (const float*)d_in[6];
  const float* Wo = (const float*)d_in[7];
  const float* bo = (const float*)d_in[8];

  char* ws = (char*)d_ws;
  u16* xb = (u16*)ws;                              // 16 MB (reused as vt after QKV GEMM)
  u16* wqkvt = (u16*)(ws + ((size_t)16 << 20));    // 6 MB
  u16* wot = (u16*)(ws + ((size_t)22 << 20));      // 2 MB
  u16* qkv = (u16*)(ws + ((size_t)24 << 20));      // 48 MB
  u16* attnO = (u16*)(ws + ((size_t)72 << 20));    // 16 MB
  float* bqkv = (float*)(ws + ((size_t)88 << 20)); // 12 KB
  u16* vtp = xb;                                   // vt aliases xb (dead after QKV GEMM)

  convert_x_kernel<<<4096, 256, 0, stream>>>(x, xb);
  transpose_w_kernel<<<dim3(32, 32, 4), 256, 0, stream>>>(Wq, Wk, Wv, Wo, wqkvt, wot);
  concat_bias_kernel<<<12, 256, 0, stream>>>(bq, bk, bv, bqkv);
  gemm_bt_kernel<1><<<dim3(64, 24), 256, 0, stream>>>(xb, wqkvt, bqkv, (void*)qkv,
                                                      MROWS, 3 * DMODEL, DMODEL);
  transpose_v_kernel<<<dim3(64, 2, 64), 256, 0, stream>>>(qkv, vtp);
  attn_kernel<<<dim3(8, BATCH * NHEAD), 256, 0, stream>>>(qkv, vtp, attnO);
  gemm_bt_kernel<0><<<dim3(64, 8), 256, 0, stream>>>(attnO, wot, bo, d_out,
                                                     MROWS, DMODEL, DMODEL);
}